// Round 16
// baseline (6563.172 us; speedup 1.0000x reference)
//
#include <hip/hip_runtime.h>
#include <math.h>

typedef __attribute__((ext_vector_type(4))) float f32x4;
typedef __attribute__((ext_vector_type(2))) float f32x2;
typedef __attribute__((ext_vector_type(8))) __bf16 bf16x8;
typedef __attribute__((ext_vector_type(4))) __bf16 bf16x4;
typedef __attribute__((ext_vector_type(4))) unsigned int u32x4;

#define DI __device__ __forceinline__

constexpr int Bd = 2, Sd = 2048, Vd = 32000, Ed = 512, Hd = 1024, MDd = 256, Pd = 4096, Wd = 128;
constexpr int BS = Bd * Sd;          // 4096 rows
constexpr int GBLK = 128;            // GRU blocks: 64 per batch group, 1024 thr
constexpr int CBLK = 96;             // conversion worker blocks in same launch

DI float sigmoidf_(float x) { return 1.0f / (1.0f + expf(-x)); }

// ---------------------------------------------------------------------------
// bf16 GEMM, m97 structure: C[M,N] = epi( A[M,K] * B[N,K]^T + bias ).
// 128x128 tile, BK=32, global_load_lds width=16 staging into LINEAR
// [128][32] bf16 LDS. EPI 0: C=acc+bias; 1: Ch=relu^2; 2: dual; 3: scatter.
// ---------------------------------------------------------------------------
template<int EPI>
__global__ __launch_bounds__(256) void gemm_h(
    const __bf16* __restrict__ A, const __bf16* __restrict__ B,
    const float* __restrict__ bias, float* __restrict__ C,
    __bf16* __restrict__ Ch,
    int M, int N, int K, int ldc,
    const float* __restrict__ gate, const float* __restrict__ msp,
    const int* __restrict__ untied)
{
  __shared__ __attribute__((aligned(16))) __bf16 As[128 * 32];  // 8 KB linear
  __shared__ __attribute__((aligned(16))) __bf16 Bs[128 * 32];  // 8 KB linear
  const int tid  = threadIdx.x;
  const int lane = tid & 63, w = tid >> 6;
  const int m0 = blockIdx.y * 128, n0 = blockIdx.x * 128;
  const int wrow = (w >> 1) * 64, wcol = (w & 1) * 64;

  f32x4 acc[4][4] = {};
  const int nk = K >> 5;

  const int srow = (w << 5) + (lane >> 2);
  const int sce  = (lane & 3) << 3;
  __bf16* lA0 = As + (w << 10);
  __bf16* lB0 = Bs + (w << 10);

  for (int kt = 0; kt < nk; ++kt) {
    const int k0 = kt << 5;
    __syncthreads();
    {
      const __bf16* ga0 = A + (size_t)(m0 + srow) * K + k0 + sce;
      const __bf16* ga1 = A + (size_t)(m0 + srow + 16) * K + k0 + sce;
      const __bf16* gb0 = B + (size_t)(n0 + srow) * K + k0 + sce;
      const __bf16* gb1 = B + (size_t)(n0 + srow + 16) * K + k0 + sce;
      __builtin_amdgcn_global_load_lds(
          (const __attribute__((address_space(1))) void*)ga0,
          (__attribute__((address_space(3))) void*)lA0, 16, 0, 0);
      __builtin_amdgcn_global_load_lds(
          (const __attribute__((address_space(1))) void*)ga1,
          (__attribute__((address_space(3))) void*)(lA0 + 512), 16, 0, 0);
      __builtin_amdgcn_global_load_lds(
          (const __attribute__((address_space(1))) void*)gb0,
          (__attribute__((address_space(3))) void*)lB0, 16, 0, 0);
      __builtin_amdgcn_global_load_lds(
          (const __attribute__((address_space(1))) void*)gb1,
          (__attribute__((address_space(3))) void*)(lB0 + 512), 16, 0, 0);
    }
    __syncthreads();

    bf16x8 af[4], bfr[4];
    #pragma unroll
    for (int t2 = 0; t2 < 4; ++t2) {
      const int ra = wrow + t2 * 16 + (lane & 15);
      const int rb = wcol + t2 * 16 + (lane & 15);
      const int cs = (lane >> 4) << 3;
      af[t2]  = *reinterpret_cast<const bf16x8*>(As + ra * 32 + cs);
      bfr[t2] = *reinterpret_cast<const bf16x8*>(Bs + rb * 32 + cs);
    }
    #pragma unroll
    for (int mi = 0; mi < 4; ++mi)
      #pragma unroll
      for (int ni = 0; ni < 4; ++ni)
        acc[mi][ni] = __builtin_amdgcn_mfma_f32_16x16x32_bf16(af[mi], bfr[ni], acc[mi][ni], 0, 0, 0);
  }

  const float ms = (EPI == 3) ? msp[0] : 0.f;
  #pragma unroll
  for (int mi = 0; mi < 4; ++mi) {
    #pragma unroll
    for (int ni = 0; ni < 4; ++ni) {
      const int cc = n0 + wcol + ni * 16 + (lane & 15);
      const float bv = bias ? bias[cc] : 0.f;
      #pragma unroll
      for (int rg = 0; rg < 4; ++rg) {
        const int rr = m0 + wrow + mi * 16 + (lane >> 4) * 4 + rg;
        const float v = acc[mi][ni][rg];
        if (EPI == 0) {
          C[(size_t)rr * ldc + cc] = v + bv;
        } else if (EPI == 1) {
          float u = fmaxf(v + bv, 0.f);
          Ch[(size_t)rr * ldc + cc] = (__bf16)(u * u);
        } else if (EPI == 2) {
          float o = v + bv;
          C[(size_t)rr * ldc + cc] = o;
          Ch[(size_t)rr * ldc + cc] = (__bf16)o;
        } else {
          float g = 1.f + gate[rr] * ms;
          atomicAdd(&C[(size_t)rr * ldc + untied[cc]], v + g * bv);
        }
      }
    }
  }
}

// f32 -> bf16 bulk convert (n multiple of 8)
__global__ __launch_bounds__(256) void convh(
    const float* __restrict__ s, __bf16* __restrict__ d, int n)
{
  const int i = (blockIdx.x * 256 + threadIdx.x) * 8;
  if (i >= n) return;
  f32x4 a = *reinterpret_cast<const f32x4*>(s + i);
  f32x4 b = *reinterpret_cast<const f32x4*>(s + i + 4);
  bf16x8 o;
  o[0] = (__bf16)a.x; o[1] = (__bf16)a.y; o[2] = (__bf16)a.z; o[3] = (__bf16)a.w;
  o[4] = (__bf16)b.x; o[5] = (__bf16)b.y; o[6] = (__bf16)b.z; o[7] = (__bf16)b.w;
  *reinterpret_cast<bf16x8*>(d + i) = o;
}

// worker-block grid-stride f32->bf16 convert (wb in [0,CBLK))
DI void conv_range(const float* __restrict__ s, __bf16* __restrict__ d,
                   size_t n, int wb, int tid)
{
  for (size_t i = ((size_t)wb * 1024 + tid) * 8; i < n; i += (size_t)CBLK * 1024 * 8) {
    f32x4 a = *reinterpret_cast<const f32x4*>(s + i);
    f32x4 b = *reinterpret_cast<const f32x4*>(s + i + 4);
    bf16x8 o;
    o[0] = (__bf16)a.x; o[1] = (__bf16)a.y; o[2] = (__bf16)a.z; o[3] = (__bf16)a.w;
    o[4] = (__bf16)b.x; o[5] = (__bf16)b.y; o[6] = (__bf16)b.z; o[7] = (__bf16)b.w;
    *reinterpret_cast<bf16x8*>(d + i) = o;
  }
}

// Device-coherent 16B poll: sc0 (L1 bypass) + sc1 (L2 bypass) reads the
// coherence point where producers' relaxed agent atomic stores land.
DI void poll2_coherent(const unsigned long long* p, u32x4& a) {
  asm volatile("global_load_dwordx4 %0, %1, off sc0 sc1\n\t"
               "s_waitcnt vmcnt(0)"
               : "=&v"(a) : "v"(p) : "memory");
}

// ---------------------------------------------------------------------------
// Persistent GRU (proven v14 structure) + 96 INDEPENDENT conversion worker
// blocks in the same launch (pure spatial overlap on otherwise-idle CUs:
// disjoint data, no shared barriers, no sync -> zero deadlock/race surface;
// stream order guarantees consumers run after the whole launch completes).
// GRU blocks (bid<128): 64 per batch group; wave wv of group-block gb owns
// ONE h-index j=gb*16+wv (3 w_hh rows in registers, 3 dot-1024s); coalesced
// tagged publish (2 full 64B lines); pollers (tid<512) touch only the poll
// address; gi prefetch + bf16 states write on non-poller threads.
// ---------------------------------------------------------------------------
__global__ __launch_bounds__(1024) void gru_kernel(
    const float* __restrict__ gi,    // [BS][3H]
    const float* __restrict__ w_hh,  // [3H][H]
    const float* __restrict__ b_hh,  // [3H]
    __bf16* __restrict__ statesh,    // [BS][H] bf16
    unsigned long long* __restrict__ hb,  // [2 parity][2 batch][Hd] {tag,val}
    const float* __restrict__ emb,  __bf16* __restrict__ embh,
    const float* __restrict__ wfc,  __bf16* __restrict__ wfc_h,
    const float* __restrict__ whp,  __bf16* __restrict__ whp_h,
    const float* __restrict__ wq,   const float* __restrict__ wk,
    const float* __restrict__ wvv,  __bf16* __restrict__ wqkv_h,
    const float* __restrict__ wph,  __bf16* __restrict__ wph_h)
{
  const int bid = blockIdx.x, tid = threadIdx.x;

  if (bid >= GBLK) {
    // ---- conversion workers: independent, no sync with GRU blocks ----
    const int wb = bid - GBLK;
    conv_range(emb, embh, (size_t)Vd * Ed, wb, tid);
    conv_range(wfc, wfc_h, (size_t)4 * Ed * Hd, wb, tid);
    conv_range(whp, whp_h, (size_t)Ed * 4 * Ed, wb, tid);
    conv_range(wq,  wqkv_h,                      (size_t)MDd * Hd, wb, tid);
    conv_range(wk,  wqkv_h + (size_t)MDd * Hd,   (size_t)MDd * Hd, wb, tid);
    conv_range(wvv, wqkv_h + (size_t)512 * Hd,   (size_t)Ed * Hd,  wb, tid);
    conv_range(wph, wph_h, (size_t)Pd * Ed, wb, tid);
    return;
  }

  __shared__ float hsm[Hd];          // this batch's h(t-1)
  __shared__ float gpre_sm[2][48];   // parity-buffered pregates for 16 h-idx
  __shared__ float pubst[16];        // publish staging: block's 16 h values
  const int lane = tid & 63, wv = tid >> 6;
  const int b  = bid >> 6;           // batch group
  const int gb = bid & 63;           // block index within group
  const int j  = gb * 16 + wv;       // this wave's h index

  // --- w_hh rows (r,z,n for j) into registers, lane-sliced (16 floats ea) ---
  f32x4 wr[4], wz[4], wn[4];
  #pragma unroll
  for (int c = 0; c < 4; ++c) {
    const int k = lane * 4 + c * 256;
    wr[c] = *reinterpret_cast<const f32x4*>(w_hh + (size_t)(0 * Hd + j) * Hd + k);
    wz[c] = *reinterpret_cast<const f32x4*>(w_hh + (size_t)(1 * Hd + j) * Hd + k);
    wn[c] = *reinterpret_cast<const f32x4*>(w_hh + (size_t)(2 * Hd + j) * Hd + k);
  }
  const float br = b_hh[j], bz = b_hh[Hd + j], bn = b_hh[2 * Hd + j];

  for (int i = tid; i < Hd; i += 1024) hsm[i] = 0.f;
  if (tid < 48) {
    const int g = tid >> 4, o = tid & 15;
    gpre_sm[0][tid] = gi[(size_t)b * Sd * 3 * Hd + g * Hd + gb * 16 + o];
  }
  __syncthreads();

  // rotated slot pair: staggers each block's L3 sweep across the slot region
  const int slot0 = (((tid & 511) + (gb << 3)) & 511) * 2;
  const bool poller = (tid < 512);

  for (int t = 0; t < Sd; ++t) {
    // ---- matvec: 3 dot-1024 per wave, weights in regs, h from LDS ----
    float d0 = 0, d1 = 0, d2 = 0;
    #pragma unroll
    for (int c = 0; c < 4; ++c) {
      f32x4 hv = *reinterpret_cast<const f32x4*>(&hsm[lane * 4 + c * 256]);
      d0 += wr[c].x*hv.x + wr[c].y*hv.y + wr[c].z*hv.z + wr[c].w*hv.w;
      d1 += wz[c].x*hv.x + wz[c].y*hv.y + wz[c].z*hv.z + wz[c].w*hv.w;
      d2 += wn[c].x*hv.x + wn[c].y*hv.y + wn[c].z*hv.z + wn[c].w*hv.w;
    }
    #pragma unroll
    for (int off = 32; off > 0; off >>= 1) {
      d0 += __shfl_xor(d0, off, 64);
      d1 += __shfl_xor(d1, off, 64);
      d2 += __shfl_xor(d2, off, 64);
    }

    const unsigned tagu = (unsigned)(t + 1);
    const unsigned long long tag = (unsigned long long)(t + 1);
    const int par = (t + 1) & 1;
    unsigned long long* hbp = hb + ((size_t)par * 2 + b) * Hd;

    // ---- gate: wave-parallel (lanes 0/1 sigmoids concurrent, tanh bcast) ----
    const float pgr = gpre_sm[t & 1][wv];
    const float pgz = gpre_sm[t & 1][16 + wv];
    const float pgn = gpre_sm[t & 1][32 + wv];
    const float a  = (lane == 0) ? (pgr + d0 + br) : (pgz + d1 + bz);
    const float sg = sigmoidf_(a);
    const float r  = __shfl(sg, 0, 64);
    const float z  = __shfl(sg, 1, 64);
    const float n  = tanhf(pgn + r * (d2 + bn));
    const float ho = hsm[j];
    const float h  = (1.f - z) * n + z * ho;
    if (lane == 0) pubst[wv] = h;

    // barrier 1: pubst ready AND every wave has finished reading hsm
    __syncthreads();

    // ---- coalesced publish: wave 0 lanes 0-15, one instruction ----
    if (tid < 16) {
      const float hv = pubst[tid];
      __hip_atomic_store(&hbp[gb * 16 + tid],
                         (tag << 32) | (unsigned long long)__float_as_uint(hv),
                         __ATOMIC_RELAXED, __HIP_MEMORY_SCOPE_AGENT);
    }

    // ---- NON-POLLER threads: gi prefetch + own-block states write ----
    if (tid >= 512 && tid < 560) {
      const int q = tid - 512;
      const int g = q >> 4, o = q & 15;
      const int tn = (t + 1 < Sd) ? (t + 1) : t;
      gpre_sm[par][q] = gi[((size_t)b * Sd + tn) * 3 * Hd + g * Hd + gb * 16 + o];
    }
    if (tid >= 576 && tid < 592) {
      const int q = tid - 576;
      statesh[((size_t)b * Sd + t) * Hd + gb * 16 + q] = (__bf16)pubst[q];
    }

    if (poller && t + 1 < Sd) {
      // ---- poll own-batch slots: one 16B device-coherent load per poller ----
      float v0 = 0, v1 = 0;
      bool done = false;
      for (int rounds = 0; rounds < 16384 && !done; ++rounds) {
        u32x4 a4;
        poll2_coherent(&hbp[slot0], a4);
        if (a4[1] == tagu && a4[3] == tagu) {
          v0 = __uint_as_float(a4[0]); v1 = __uint_as_float(a4[2]);
          done = true;
        } else if (rounds >= 6) {
          __builtin_amdgcn_s_sleep(1);   // pace stragglers
        }
      }
      if (!done) {
        // guaranteed-progress fallback: 8B atomic loads (proven path)
        bool f0 = false, f1 = false;
        do {
          unsigned long long x0, x1;
          if (!f0) x0 = __hip_atomic_load(&hbp[slot0 + 0], __ATOMIC_RELAXED, __HIP_MEMORY_SCOPE_AGENT);
          if (!f1) x1 = __hip_atomic_load(&hbp[slot0 + 1], __ATOMIC_RELAXED, __HIP_MEMORY_SCOPE_AGENT);
          if (!f0 && (x0 >> 32) == tag) { v0 = __uint_as_float((unsigned)x0); f0 = true; }
          if (!f1 && (x1 >> 32) == tag) { v1 = __uint_as_float((unsigned)x1); f1 = true; }
        } while (!(f0 && f1));
      }
      hsm[slot0]     = v0;
      hsm[slot0 + 1] = v1;
    }
    __syncthreads();   // hsm fully updated before next matvec
  }
}

// ---------------------------------------------------------------------------
__global__ __launch_bounds__(128) void embed_kernel(
    const int* __restrict__ ids, const float* __restrict__ emb, __bf16* __restrict__ xh)
{
  const int row = blockIdx.x;
  const int tok = ids[row];
  f32x4 v = reinterpret_cast<const f32x4*>(emb + (size_t)tok * Ed)[threadIdx.x];
  bf16x4 o;
  o[0] = (__bf16)v.x; o[1] = (__bf16)v.y; o[2] = (__bf16)v.z; o[3] = (__bf16)v.w;
  reinterpret_cast<bf16x4*>(xh + (size_t)row * Ed)[threadIdx.x] = o;
}

__global__ __launch_bounds__(256) void gate_kernel(
    const __bf16* __restrict__ statesh, const float* __restrict__ wg,
    const float* __restrict__ bg, float* __restrict__ gate)
{
  const int row = blockIdx.x * 4 + (threadIdx.x >> 6);
  const int lane = threadIdx.x & 63;
  const __bf16* sp = statesh + (size_t)row * Hd + lane * 16;
  bf16x8 a0 = *reinterpret_cast<const bf16x8*>(sp);
  bf16x8 a1 = *reinterpret_cast<const bf16x8*>(sp + 8);
  float s = 0;
  #pragma unroll
  for (int i = 0; i < 8; ++i)
    s += (float)a0[i] * wg[lane * 16 + i] + (float)a1[i] * wg[lane * 16 + 8 + i];
  #pragma unroll
  for (int off = 32; off > 0; off >>= 1) s += __shfl_down(s, off, 64);
  if (lane == 0) gate[row] = sigmoidf_(s + bg[0]);
}

// windowed attention over packed qkv[BS][1024] (q@0,k@256,v@512), 512 thr;
// writes fused bf16 feat: ffh = bf16(featb + gate*ms*ctx)
__global__ __launch_bounds__(512) void attn_kernel(
    const float* __restrict__ qkv, const float* __restrict__ featb,
    __bf16* __restrict__ ffh,
    const float* __restrict__ gate, const float* __restrict__ msp)
{
  const int row = blockIdx.x;
  const int b = row >> 11, qi = row & (Sd - 1);
  const int tid = threadIdx.x, lane = tid & 63, wv = tid >> 6;
  __shared__ float qs[MDd];
  __shared__ float sc[Wd];
  if (tid < MDd) qs[tid] = qkv[(size_t)row * 1024 + tid];
  __syncthreads();
  const int lo = (qi > Wd) ? (qi - Wd) : 0;
  const int len = qi - lo;
  const float gm = gate[row] * msp[0];
  for (int jj = wv; jj < len; jj += 8) {
    const float* kr = qkv + (size_t)(b * Sd + lo + jj) * 1024 + 256;
    f32x4 kv = *reinterpret_cast<const f32x4*>(kr + lane * 4);
    f32x4 qv = *reinterpret_cast<const f32x4*>(&qs[lane * 4]);
    float s = kv.x * qv.x + kv.y * qv.y + kv.z * qv.z + kv.w * qv.w;
    #pragma unroll
    for (int off = 32; off > 0; off >>= 1) s += __shfl_down(s, off, 64);
    if (lane == 0) sc[jj] = s * 0.0625f;
  }
  __syncthreads();
  if (wv == 0 && len > 0) {
    float m = -3.4e38f;
    for (int jj = lane; jj < len; jj += 64) m = fmaxf(m, sc[jj]);
    #pragma unroll
    for (int off = 32; off > 0; off >>= 1) m = fmaxf(m, __shfl_xor(m, off, 64));
    float ssum = 0;
    for (int jj = lane; jj < len; jj += 64) { float e = expf(sc[jj] - m); sc[jj] = e; ssum += e; }
    #pragma unroll
    for (int off = 32; off > 0; off >>= 1) ssum += __shfl_xor(ssum, off, 64);
    const float inv = 1.f / ssum;
    for (int jj = lane; jj < len; jj += 64) sc[jj] *= inv;
  }
  __syncthreads();
  {
    const int e = tid;                 // Ed=512 covered in one pass
    float a = 0;
    for (int jj = 0; jj < len; ++jj)
      a += sc[jj] * qkv[(size_t)(b * Sd + lo + jj) * 1024 + 512 + e];
    ffh[(size_t)row * Ed + e] = (__bf16)(featb[(size_t)row * Ed + e] + gm * a);
  }
}

// ---------------------------------------------------------------------------
extern "C" void kernel_launch(void* const* d_in, const int* in_sizes, int n_in,
                              void* d_out, int out_size, void* d_ws, size_t ws_size,
                              hipStream_t stream)
{
  const int*   ids    = (const int*)d_in[0];
  const int*   untied = (const int*)d_in[1];
  const float* emb    = (const float*)d_in[2];
  const float* w_ih   = (const float*)d_in[3];
  const float* w_hh   = (const float*)d_in[4];
  const float* b_ih   = (const float*)d_in[5];
  const float* b_hh   = (const float*)d_in[6];
  const float* wq     = (const float*)d_in[7];
  const float* bq     = (const float*)d_in[8];
  const float* wk     = (const float*)d_in[9];
  const float* bk     = (const float*)d_in[10];
  const float* wv     = (const float*)d_in[11];
  const float* bv     = (const float*)d_in[12];
  const float* wg     = (const float*)d_in[13];
  const float* bg     = (const float*)d_in[14];
  const float* w_fc   = (const float*)d_in[15];
  const float* b_fc   = (const float*)d_in[16];
  const float* w_hp   = (const float*)d_in[17];
  const float* b_hp   = (const float*)d_in[18];
  const float* out_b  = (const float*)d_in[19];
  const float* w_ph   = (const float*)d_in[20];
  const float* b_ph   = (const float*)d_in[21];
  const float* msc    = (const float*)d_in[22];
  float* out = (float*)d_out;

  // ---- workspace layout (bytes, 256-aligned) ----
  char* W = (char*)d_ws;
  size_t off = 0;
  auto nxt = [&](size_t bytes) { char* p = W + off; off += (bytes + 255) & ~(size_t)255; return p; };
  float*  gi      = (float*) nxt((size_t)BS * 3 * Hd * 4);   // 50.3 MB (freed after GRU)
  __bf16* statesh = (__bf16*)nxt((size_t)BS * Hd * 2);       // 8.4 MB
  float*  featb   = (float*) nxt((size_t)BS * Ed * 4);       // 8.4 MB
  __bf16* embh    = (__bf16*)nxt((size_t)Vd * Ed * 2);       // 32.8 MB
  __bf16* wih_h   = (__bf16*)nxt((size_t)3 * Hd * Ed * 2);   // 3.1 MB
  __bf16* wfc_h   = (__bf16*)nxt((size_t)4 * Ed * Hd * 2);   // 4.2 MB
  __bf16* whp_h   = (__bf16*)nxt((size_t)Ed * 4 * Ed * 2);   // 2.1 MB
  __bf16* wqkv_h  = (__bf16*)nxt((size_t)1024 * Hd * 2);     // 2.1 MB (q|k|v rows)
  __bf16* wph_h   = (__bf16*)nxt((size_t)Pd * Ed * 2);       // 4.2 MB
  __bf16* xh      = (__bf16*)nxt((size_t)BS * Ed * 2);       // 4.2 MB
  float*  bqkv    = (float*) nxt(1024 * 4);
  unsigned long long* hb = (unsigned long long*)nxt(2 * 2 * Hd * 8);
  float*  gateb   = (float*) nxt((size_t)BS * 4);
  // overlay in gi region (gi consumed by GRU before these are written):
  __bf16* hfh    = (__bf16*)gi;                              // 16.8 MB
  __bf16* feat_h = (__bf16*)((char*)gi + 16777216);          // 4.2 MB
  __bf16* ffh    = (__bf16*)((char*)gi + 20971520);          // 4.2 MB
  float*  qkv    = (float*) ((char*)gi + 25165824);          // 16.8 MB (ends 41.9MB)

  hipMemsetAsync(hb, 0, 2 * 2 * Hd * sizeof(unsigned long long), stream);

  // ---- pre-GRU: only wih_h needed before the gi GEMM ----
  convh<<<(int)(((size_t)3 * Hd * Ed / 8 + 255) / 256), 256, 0, stream>>>(
      w_ih, wih_h, 3 * Hd * Ed);
  hipMemcpyAsync(bqkv,       bq, MDd * 4, hipMemcpyDeviceToDevice, stream);
  hipMemcpyAsync(bqkv + MDd, bk, MDd * 4, hipMemcpyDeviceToDevice, stream);
  hipMemcpyAsync(bqkv + 512, bv, Ed * 4,  hipMemcpyDeviceToDevice, stream);

  // x = bf16(emb[ids])
  embed_kernel<<<BS, 128, 0, stream>>>(ids, emb, xh);
  // gi = x @ w_ih^T + b_ih  (f32 out, GRU precision)
  gemm_h<0><<<dim3(3 * Hd / 128, BS / 128), 256, 0, stream>>>(
      xh, wih_h, b_ih, gi, nullptr, BS, 3 * Hd, Ed, 3 * Hd, nullptr, nullptr, nullptr);
  // states = GRU(gi) -> bf16; +96 worker blocks do the big weight
  // conversions concurrently on otherwise-idle CUs (no sync, disjoint data)
  gru_kernel<<<GBLK + CBLK, 1024, 0, stream>>>(
      gi, w_hh, b_hh, statesh, hb,
      emb, embh, w_fc, wfc_h, w_hp, whp_h, wq, wk, wv, wqkv_h, w_ph, wph_h);
  // hf = bf16(relu(states @ w_fc^T + b_fc)^2)
  gemm_h<1><<<dim3(4 * Ed / 128, BS / 128), 256, 0, stream>>>(
      statesh, wfc_h, b_fc, nullptr, hfh, BS, 4 * Ed, Hd, 4 * Ed, nullptr, nullptr, nullptr);
  // base_feat = hf @ w_hp^T + b_hp  (f32 + bf16 dual)
  gemm_h<2><<<dim3(Ed / 128, BS / 128), 256, 0, stream>>>(
      hfh, whp_h, b_hp, featb, feat_h, BS, Ed, 4 * Ed, Ed, nullptr, nullptr, nullptr);
  // base_logits = base_feat @ emb^T + out_bias  -> d_out
  gemm_h<0><<<dim3(Vd / 128, BS / 128), 256, 0, stream>>>(
      feat_h, embh, out_b, out, nullptr, BS, Vd, Ed, Vd, nullptr, nullptr, nullptr);
  // qkv = states @ [wq|wk|wv]^T + [bq|bk|bv]  (one N=1024 GEMM)
  gemm_h<0><<<dim3(1024 / 128, BS / 128), 256, 0, stream>>>(
      statesh, wqkv_h, bqkv, qkv, nullptr, BS, 1024, Hd, 1024, nullptr, nullptr, nullptr);
  // gate
  gate_kernel<<<BS / 4, 256, 0, stream>>>(statesh, wg, bg, gateb);
  // ctx = windowed attention; ffh = bf16(featb + gate*ms*ctx)
  attn_kernel<<<BS, 512, 0, stream>>>(qkv, featb, ffh, gateb, msc);
  // scatter: d_out[r, untied[c]] += fused_feat @ w_ph^T + (1+gate*ms)*b_ph
  gemm_h<3><<<dim3(Pd / 128, BS / 128), 256, 0, stream>>>(
      ffh, wph_h, b_ph, out, nullptr, BS, Pd, Ed, Vd, gateb, msc, untied);
}

// Round 17
// 6380.586 us; speedup vs baseline: 1.0286x; 1.0286x over previous
//
#include <hip/hip_runtime.h>
#include <math.h>

typedef __attribute__((ext_vector_type(4))) float f32x4;
typedef __attribute__((ext_vector_type(2))) float f32x2;
typedef __attribute__((ext_vector_type(8))) __bf16 bf16x8;
typedef __attribute__((ext_vector_type(4))) __bf16 bf16x4;
typedef __attribute__((ext_vector_type(4))) unsigned int u32x4;

#define DI __device__ __forceinline__

constexpr int Bd = 2, Sd = 2048, Vd = 32000, Ed = 512, Hd = 1024, MDd = 256, Pd = 4096, Wd = 128;
constexpr int BS = Bd * Sd;          // 4096 rows
constexpr int GBLK = 128;            // GRU blocks: 64 per batch group, 1024 thr

DI float sigmoidf_(float x) { return 1.0f / (1.0f + expf(-x)); }

// ---------------------------------------------------------------------------
// bf16 GEMM, m97 structure: C[M,N] = epi( A[M,K] * B[N,K]^T + bias ).
// 128x128 tile, BK=32, global_load_lds width=16 staging into LINEAR
// [128][32] bf16 LDS. EPI 0: C=acc+bias; 1: Ch=relu^2; 2: dual; 3: scatter.
// ---------------------------------------------------------------------------
template<int EPI>
__global__ __launch_bounds__(256) void gemm_h(
    const __bf16* __restrict__ A, const __bf16* __restrict__ B,
    const float* __restrict__ bias, float* __restrict__ C,
    __bf16* __restrict__ Ch,
    int M, int N, int K, int ldc,
    const float* __restrict__ gate, const float* __restrict__ msp,
    const int* __restrict__ untied)
{
  __shared__ __attribute__((aligned(16))) __bf16 As[128 * 32];  // 8 KB linear
  __shared__ __attribute__((aligned(16))) __bf16 Bs[128 * 32];  // 8 KB linear
  const int tid  = threadIdx.x;
  const int lane = tid & 63, w = tid >> 6;
  const int m0 = blockIdx.y * 128, n0 = blockIdx.x * 128;
  const int wrow = (w >> 1) * 64, wcol = (w & 1) * 64;

  f32x4 acc[4][4] = {};
  const int nk = K >> 5;

  const int srow = (w << 5) + (lane >> 2);
  const int sce  = (lane & 3) << 3;
  __bf16* lA0 = As + (w << 10);
  __bf16* lB0 = Bs + (w << 10);

  for (int kt = 0; kt < nk; ++kt) {
    const int k0 = kt << 5;
    __syncthreads();
    {
      const __bf16* ga0 = A + (size_t)(m0 + srow) * K + k0 + sce;
      const __bf16* ga1 = A + (size_t)(m0 + srow + 16) * K + k0 + sce;
      const __bf16* gb0 = B + (size_t)(n0 + srow) * K + k0 + sce;
      const __bf16* gb1 = B + (size_t)(n0 + srow + 16) * K + k0 + sce;
      __builtin_amdgcn_global_load_lds(
          (const __attribute__((address_space(1))) void*)ga0,
          (__attribute__((address_space(3))) void*)lA0, 16, 0, 0);
      __builtin_amdgcn_global_load_lds(
          (const __attribute__((address_space(1))) void*)ga1,
          (__attribute__((address_space(3))) void*)(lA0 + 512), 16, 0, 0);
      __builtin_amdgcn_global_load_lds(
          (const __attribute__((address_space(1))) void*)gb0,
          (__attribute__((address_space(3))) void*)lB0, 16, 0, 0);
      __builtin_amdgcn_global_load_lds(
          (const __attribute__((address_space(1))) void*)gb1,
          (__attribute__((address_space(3))) void*)(lB0 + 512), 16, 0, 0);
    }
    __syncthreads();

    bf16x8 af[4], bfr[4];
    #pragma unroll
    for (int t2 = 0; t2 < 4; ++t2) {
      const int ra = wrow + t2 * 16 + (lane & 15);
      const int rb = wcol + t2 * 16 + (lane & 15);
      const int cs = (lane >> 4) << 3;
      af[t2]  = *reinterpret_cast<const bf16x8*>(As + ra * 32 + cs);
      bfr[t2] = *reinterpret_cast<const bf16x8*>(Bs + rb * 32 + cs);
    }
    #pragma unroll
    for (int mi = 0; mi < 4; ++mi)
      #pragma unroll
      for (int ni = 0; ni < 4; ++ni)
        acc[mi][ni] = __builtin_amdgcn_mfma_f32_16x16x32_bf16(af[mi], bfr[ni], acc[mi][ni], 0, 0, 0);
  }

  const float ms = (EPI == 3) ? msp[0] : 0.f;
  #pragma unroll
  for (int mi = 0; mi < 4; ++mi) {
    #pragma unroll
    for (int ni = 0; ni < 4; ++ni) {
      const int cc = n0 + wcol + ni * 16 + (lane & 15);
      const float bv = bias ? bias[cc] : 0.f;
      #pragma unroll
      for (int rg = 0; rg < 4; ++rg) {
        const int rr = m0 + wrow + mi * 16 + (lane >> 4) * 4 + rg;
        const float v = acc[mi][ni][rg];
        if (EPI == 0) {
          C[(size_t)rr * ldc + cc] = v + bv;
        } else if (EPI == 1) {
          float u = fmaxf(v + bv, 0.f);
          Ch[(size_t)rr * ldc + cc] = (__bf16)(u * u);
        } else if (EPI == 2) {
          float o = v + bv;
          C[(size_t)rr * ldc + cc] = o;
          Ch[(size_t)rr * ldc + cc] = (__bf16)o;
        } else {
          float g = 1.f + gate[rr] * ms;
          atomicAdd(&C[(size_t)rr * ldc + untied[cc]], v + g * bv);
        }
      }
    }
  }
}

// f32 -> bf16 bulk convert (n multiple of 8)
__global__ __launch_bounds__(256) void convh(
    const float* __restrict__ s, __bf16* __restrict__ d, int n)
{
  const int i = (blockIdx.x * 256 + threadIdx.x) * 8;
  if (i >= n) return;
  f32x4 a = *reinterpret_cast<const f32x4*>(s + i);
  f32x4 b = *reinterpret_cast<const f32x4*>(s + i + 4);
  bf16x8 o;
  o[0] = (__bf16)a.x; o[1] = (__bf16)a.y; o[2] = (__bf16)a.z; o[3] = (__bf16)a.w;
  o[4] = (__bf16)b.x; o[5] = (__bf16)b.y; o[6] = (__bf16)b.z; o[7] = (__bf16)b.w;
  *reinterpret_cast<bf16x8*>(d + i) = o;
}

// Device-coherent 16B poll: sc0 (L1 bypass) + sc1 (L2 bypass) reads the
// coherence point where producers' relaxed agent atomic stores land.
DI void poll2_coherent(const unsigned long long* p, u32x4& a) {
  asm volatile("global_load_dwordx4 %0, %1, off sc0 sc1\n\t"
               "s_waitcnt vmcnt(0)"
               : "=&v"(a) : "v"(p) : "memory");
}

// ---------------------------------------------------------------------------
// Persistent GRU — v13 arrangement (fastest measured: 4.92 ms) with bf16
// states. 128 blocks x 1024 threads, two independent groups of 64 (one per
// batch); wave wv of group-block gb owns ONE h-index j = gb*16+wv (3 w_hh
// rows in registers, 3 dot-1024s). Coalesced publish: lane 0 of each wave
// stages h to LDS; barrier (also enforces all-hsm-reads-done); lanes 0-15
// of wave 0 store the block's 16 tagged u64 slots as one wave instruction
// (2 full 64B lines). gi prefetch on tid 64-112; writer blocks (gb==0,
// rotation 0) store bf16 states coalesced from polled values. Bounded
// device-coherent poll + atomic-load fallback guarantees progress.
// ---------------------------------------------------------------------------
__global__ __launch_bounds__(1024) void gru_kernel(
    const float* __restrict__ gi,    // [BS][3H]
    const float* __restrict__ w_hh,  // [3H][H]
    const float* __restrict__ b_hh,  // [3H]
    __bf16* __restrict__ statesh,    // [BS][H] bf16
    unsigned long long* __restrict__ hb)  // [2 parity][2 batch][Hd] {tag,val}
{
  __shared__ float hsm[Hd];          // this batch's h(t-1)
  __shared__ float gpre_sm[2][48];   // parity-buffered pregates for 16 h-idx
  __shared__ float pubst[16];        // publish staging: block's 16 h values
  const int bid = blockIdx.x, tid = threadIdx.x;
  const int lane = tid & 63, wv = tid >> 6;
  const int b  = bid >> 6;           // batch group
  const int gb = bid & 63;           // block index within group
  const int j  = gb * 16 + wv;       // this wave's h index

  // --- w_hh rows (r,z,n for j) into registers, lane-sliced (16 floats ea) ---
  f32x4 wr[4], wz[4], wn[4];
  #pragma unroll
  for (int c = 0; c < 4; ++c) {
    const int k = lane * 4 + c * 256;
    wr[c] = *reinterpret_cast<const f32x4*>(w_hh + (size_t)(0 * Hd + j) * Hd + k);
    wz[c] = *reinterpret_cast<const f32x4*>(w_hh + (size_t)(1 * Hd + j) * Hd + k);
    wn[c] = *reinterpret_cast<const f32x4*>(w_hh + (size_t)(2 * Hd + j) * Hd + k);
  }
  const float br = b_hh[j], bz = b_hh[Hd + j], bn = b_hh[2 * Hd + j];

  for (int i = tid; i < Hd; i += 1024) hsm[i] = 0.f;
  if (tid < 48) {
    const int g = tid >> 4, o = tid & 15;
    gpre_sm[0][tid] = gi[(size_t)b * Sd * 3 * Hd + g * Hd + gb * 16 + o];
  }
  __syncthreads();

  // rotated slot pair: staggers each block's L3 sweep; gb==0 -> rotation 0
  const int slot0 = (((tid & 511) + (gb << 3)) & 511) * 2;
  const bool poller = (tid < 512);
  const bool writer = (gb == 0);

  for (int t = 0; t < Sd; ++t) {
    // ---- matvec: 3 dot-1024 per wave, weights in regs, h from LDS ----
    float d0 = 0, d1 = 0, d2 = 0;
    #pragma unroll
    for (int c = 0; c < 4; ++c) {
      f32x4 hv = *reinterpret_cast<const f32x4*>(&hsm[lane * 4 + c * 256]);
      d0 += wr[c].x*hv.x + wr[c].y*hv.y + wr[c].z*hv.z + wr[c].w*hv.w;
      d1 += wz[c].x*hv.x + wz[c].y*hv.y + wz[c].z*hv.z + wz[c].w*hv.w;
      d2 += wn[c].x*hv.x + wn[c].y*hv.y + wn[c].z*hv.z + wn[c].w*hv.w;
    }
    #pragma unroll
    for (int off = 32; off > 0; off >>= 1) {
      d0 += __shfl_xor(d0, off, 64);
      d1 += __shfl_xor(d1, off, 64);
      d2 += __shfl_xor(d2, off, 64);
    }

    const unsigned tagu = (unsigned)(t + 1);
    const unsigned long long tag = (unsigned long long)(t + 1);
    const int par = (t + 1) & 1;
    unsigned long long* hbp = hb + ((size_t)par * 2 + b) * Hd;

    // ---- gate: wave-parallel (lanes 0/1 sigmoids concurrent, tanh bcast) ----
    const float pgr = gpre_sm[t & 1][wv];
    const float pgz = gpre_sm[t & 1][16 + wv];
    const float pgn = gpre_sm[t & 1][32 + wv];
    const float a  = (lane == 0) ? (pgr + d0 + br) : (pgz + d1 + bz);
    const float sg = sigmoidf_(a);
    const float r  = __shfl(sg, 0, 64);
    const float z  = __shfl(sg, 1, 64);
    const float n  = tanhf(pgn + r * (d2 + bn));
    const float ho = hsm[j];
    const float h  = (1.f - z) * n + z * ho;
    if (lane == 0) pubst[wv] = h;

    // barrier 1: pubst ready AND every wave has finished reading hsm
    __syncthreads();

    // ---- coalesced publish: wave 0 lanes 0-15, one instruction,
    //      16 consecutive u64 -> 2 full 64B-line writes ----
    if (tid < 16) {
      const float hv = pubst[tid];
      __hip_atomic_store(&hbp[gb * 16 + tid],
                         (tag << 32) | (unsigned long long)__float_as_uint(hv),
                         __ATOMIC_RELAXED, __HIP_MEMORY_SCOPE_AGENT);
    }

    // ---- coalesced gi prefetch for t+1 into the other parity buffer ----
    if (tid >= 64 && tid < 112) {
      const int q = tid - 64;
      const int g = q >> 4, o = q & 15;
      const int tn = (t + 1 < Sd) ? (t + 1) : t;
      gpre_sm[par][q] = gi[((size_t)b * Sd + tn) * 3 * Hd + g * Hd + gb * 16 + o];
    }

    if (poller && (t + 1 < Sd || writer)) {
      // ---- poll own-batch slots: one 16B device-coherent load per poller ----
      float v0 = 0, v1 = 0;
      bool done = false;
      for (int rounds = 0; rounds < 16384 && !done; ++rounds) {
        u32x4 a4;
        poll2_coherent(&hbp[slot0], a4);
        if (a4[1] == tagu && a4[3] == tagu) {
          v0 = __uint_as_float(a4[0]); v1 = __uint_as_float(a4[2]);
          done = true;
        } else if (rounds >= 6) {
          __builtin_amdgcn_s_sleep(1);   // pace stragglers
        }
      }
      if (!done) {
        // guaranteed-progress fallback: 8B atomic loads (proven path)
        bool f0 = false, f1 = false;
        do {
          unsigned long long x0, x1;
          if (!f0) x0 = __hip_atomic_load(&hbp[slot0 + 0], __ATOMIC_RELAXED, __HIP_MEMORY_SCOPE_AGENT);
          if (!f1) x1 = __hip_atomic_load(&hbp[slot0 + 1], __ATOMIC_RELAXED, __HIP_MEMORY_SCOPE_AGENT);
          if (!f0 && (x0 >> 32) == tag) { v0 = __uint_as_float((unsigned)x0); f0 = true; }
          if (!f1 && (x1 >> 32) == tag) { v1 = __uint_as_float((unsigned)x1); f1 = true; }
        } while (!(f0 && f1));
      }
      if (writer) {
        // rotation 0 -> slot0 = tid*2: fully coalesced 4B/thread bf16 store
        bf16x2_s: ;
        __bf16 o0 = (__bf16)v0, o1 = (__bf16)v1;
        unsigned short u0 = *reinterpret_cast<unsigned short*>(&o0);
        unsigned short u1 = *reinterpret_cast<unsigned short*>(&o1);
        unsigned pack = (unsigned)u0 | ((unsigned)u1 << 16);
        *reinterpret_cast<unsigned*>(statesh + ((size_t)b * Sd + t) * Hd + slot0) = pack;
      }
      hsm[slot0]     = v0;
      hsm[slot0 + 1] = v1;
    }
    __syncthreads();   // hsm fully updated before next matvec
  }
}

// ---------------------------------------------------------------------------
__global__ __launch_bounds__(128) void embed_kernel(
    const int* __restrict__ ids, const float* __restrict__ emb, __bf16* __restrict__ xh)
{
  const int row = blockIdx.x;
  const int tok = ids[row];
  f32x4 v = reinterpret_cast<const f32x4*>(emb + (size_t)tok * Ed)[threadIdx.x];
  bf16x4 o;
  o[0] = (__bf16)v.x; o[1] = (__bf16)v.y; o[2] = (__bf16)v.z; o[3] = (__bf16)v.w;
  reinterpret_cast<bf16x4*>(xh + (size_t)row * Ed)[threadIdx.x] = o;
}

__global__ __launch_bounds__(256) void gate_kernel(
    const __bf16* __restrict__ statesh, const float* __restrict__ wg,
    const float* __restrict__ bg, float* __restrict__ gate)
{
  const int row = blockIdx.x * 4 + (threadIdx.x >> 6);
  const int lane = threadIdx.x & 63;
  const __bf16* sp = statesh + (size_t)row * Hd + lane * 16;
  bf16x8 a0 = *reinterpret_cast<const bf16x8*>(sp);
  bf16x8 a1 = *reinterpret_cast<const bf16x8*>(sp + 8);
  float s = 0;
  #pragma unroll
  for (int i = 0; i < 8; ++i)
    s += (float)a0[i] * wg[lane * 16 + i] + (float)a1[i] * wg[lane * 16 + 8 + i];
  #pragma unroll
  for (int off = 32; off > 0; off >>= 1) s += __shfl_down(s, off, 64);
  if (lane == 0) gate[row] = sigmoidf_(s + bg[0]);
}

// windowed attention over packed qkv[BS][1024] (q@0,k@256,v@512), 512 thr;
// writes fused bf16 feat: ffh = bf16(featb + gate*ms*ctx)
__global__ __launch_bounds__(512) void attn_kernel(
    const float* __restrict__ qkv, const float* __restrict__ featb,
    __bf16* __restrict__ ffh,
    const float* __restrict__ gate, const float* __restrict__ msp)
{
  const int row = blockIdx.x;
  const int b = row >> 11, qi = row & (Sd - 1);
  const int tid = threadIdx.x, lane = tid & 63, wv = tid >> 6;
  __shared__ float qs[MDd];
  __shared__ float sc[Wd];
  if (tid < MDd) qs[tid] = qkv[(size_t)row * 1024 + tid];
  __syncthreads();
  const int lo = (qi > Wd) ? (qi - Wd) : 0;
  const int len = qi - lo;
  const float gm = gate[row] * msp[0];
  for (int jj = wv; jj < len; jj += 8) {
    const float* kr = qkv + (size_t)(b * Sd + lo + jj) * 1024 + 256;
    f32x4 kv = *reinterpret_cast<const f32x4*>(kr + lane * 4);
    f32x4 qv = *reinterpret_cast<const f32x4*>(&qs[lane * 4]);
    float s = kv.x * qv.x + kv.y * qv.y + kv.z * qv.z + kv.w * qv.w;
    #pragma unroll
    for (int off = 32; off > 0; off >>= 1) s += __shfl_down(s, off, 64);
    if (lane == 0) sc[jj] = s * 0.0625f;
  }
  __syncthreads();
  if (wv == 0 && len > 0) {
    float m = -3.4e38f;
    for (int jj = lane; jj < len; jj += 64) m = fmaxf(m, sc[jj]);
    #pragma unroll
    for (int off = 32; off > 0; off >>= 1) m = fmaxf(m, __shfl_xor(m, off, 64));
    float ssum = 0;
    for (int jj = lane; jj < len; jj += 64) { float e = expf(sc[jj] - m); sc[jj] = e; ssum += e; }
    #pragma unroll
    for (int off = 32; off > 0; off >>= 1) ssum += __shfl_xor(ssum, off, 64);
    const float inv = 1.f / ssum;
    for (int jj = lane; jj < len; jj += 64) sc[jj] *= inv;
  }
  __syncthreads();
  {
    const int e = tid;                 // Ed=512 covered in one pass
    float a = 0;
    for (int jj = 0; jj < len; ++jj)
      a += sc[jj] * qkv[(size_t)(b * Sd + lo + jj) * 1024 + 512 + e];
    ffh[(size_t)row * Ed + e] = (__bf16)(featb[(size_t)row * Ed + e] + gm * a);
  }
}

// ---------------------------------------------------------------------------
extern "C" void kernel_launch(void* const* d_in, const int* in_sizes, int n_in,
                              void* d_out, int out_size, void* d_ws, size_t ws_size,
                              hipStream_t stream)
{
  const int*   ids    = (const int*)d_in[0];
  const int*   untied = (const int*)d_in[1];
  const float* emb    = (const float*)d_in[2];
  const float* w_ih   = (const float*)d_in[3];
  const float* w_hh   = (const float*)d_in[4];
  const float* b_ih   = (const float*)d_in[5];
  const float* b_hh   = (const float*)d_in[6];
  const float* wq     = (const float*)d_in[7];
  const float* bq     = (const float*)d_in[8];
  const float* wk     = (const float*)d_in[9];
  const float* bk     = (const float*)d_in[10];
  const float* wv     = (const float*)d_in[11];
  const float* bv     = (const float*)d_in[12];
  const float* wg     = (const float*)d_in[13];
  const float* bg     = (const float*)d_in[14];
  const float* w_fc   = (const float*)d_in[15];
  const float* b_fc   = (const float*)d_in[16];
  const float* w_hp   = (const float*)d_in[17];
  const float* b_hp   = (const float*)d_in[18];
  const float* out_b  = (const float*)d_in[19];
  const float* w_ph   = (const float*)d_in[20];
  const float* b_ph   = (const float*)d_in[21];
  const float* msc    = (const float*)d_in[22];
  float* out = (float*)d_out;

  // ---- workspace layout (bytes, 256-aligned) ----
  char* W = (char*)d_ws;
  size_t off = 0;
  auto nxt = [&](size_t bytes) { char* p = W + off; off += (bytes + 255) & ~(size_t)255; return p; };
  float*  gi      = (float*) nxt((size_t)BS * 3 * Hd * 4);   // 50.3 MB (freed after GRU)
  __bf16* statesh = (__bf16*)nxt((size_t)BS * Hd * 2);       // 8.4 MB
  float*  featb   = (float*) nxt((size_t)BS * Ed * 4);       // 8.4 MB
  __bf16* embh    = (__bf16*)nxt((size_t)Vd * Ed * 2);       // 32.8 MB
  __bf16* wih_h   = (__bf16*)nxt((size_t)3 * Hd * Ed * 2);   // 3.1 MB
  __bf16* wfc_h   = (__bf16*)nxt((size_t)4 * Ed * Hd * 2);   // 4.2 MB
  __bf16* whp_h   = (__bf16*)nxt((size_t)Ed * 4 * Ed * 2);   // 2.1 MB
  __bf16* wqkv_h  = (__bf16*)nxt((size_t)1024 * Hd * 2);     // 2.1 MB (q|k|v rows)
  __bf16* wph_h   = (__bf16*)nxt((size_t)Pd * Ed * 2);       // 4.2 MB
  __bf16* xh      = (__bf16*)nxt((size_t)BS * Ed * 2);       // 4.2 MB
  float*  bqkv    = (float*) nxt(1024 * 4);
  unsigned long long* hb = (unsigned long long*)nxt(2 * 2 * Hd * 8);
  float*  gateb   = (float*) nxt((size_t)BS * 4);
  // overlay in gi region (gi consumed by GRU before these are written):
  __bf16* hfh    = (__bf16*)gi;                              // 16.8 MB
  __bf16* feat_h = (__bf16*)((char*)gi + 16777216);          // 4.2 MB
  __bf16* ffh    = (__bf16*)((char*)gi + 20971520);          // 4.2 MB
  float*  qkv    = (float*) ((char*)gi + 25165824);          // 16.8 MB (ends 41.9MB)

  hipMemsetAsync(hb, 0, 2 * 2 * Hd * sizeof(unsigned long long), stream);

  // ---- one-time f32->bf16 conversions (weights + emb) ----
  auto cv = [&](const float* s, __bf16* d, size_t n) {
    convh<<<(int)((n / 8 + 255) / 256), 256, 0, stream>>>(s, d, (int)n);
  };
  cv(emb,  embh,  (size_t)Vd * Ed);
  cv(w_ih, wih_h, (size_t)3 * Hd * Ed);
  cv(w_fc, wfc_h, (size_t)4 * Ed * Hd);
  cv(w_hp, whp_h, (size_t)Ed * 4 * Ed);
  cv(wq,   wqkv_h,                 (size_t)MDd * Hd);
  cv(wk,   wqkv_h + (size_t)MDd * Hd,  (size_t)MDd * Hd);
  cv(wv,   wqkv_h + (size_t)512 * Hd,  (size_t)Ed * Hd);
  cv(w_ph, wph_h, (size_t)Pd * Ed);
  hipMemcpyAsync(bqkv,       bq, MDd * 4, hipMemcpyDeviceToDevice, stream);
  hipMemcpyAsync(bqkv + MDd, bk, MDd * 4, hipMemcpyDeviceToDevice, stream);
  hipMemcpyAsync(bqkv + 512, bv, Ed * 4,  hipMemcpyDeviceToDevice, stream);

  // x = bf16(emb[ids])
  embed_kernel<<<BS, 128, 0, stream>>>(ids, emb, xh);
  // gi = x @ w_ih^T + b_ih  (f32 out, GRU precision)
  gemm_h<0><<<dim3(3 * Hd / 128, BS / 128), 256, 0, stream>>>(
      xh, wih_h, b_ih, gi, nullptr, BS, 3 * Hd, Ed, 3 * Hd, nullptr, nullptr, nullptr);
  // states = GRU(gi) -> bf16
  gru_kernel<<<GBLK, 1024, 0, stream>>>(gi, w_hh, b_hh, statesh, hb);
  // hf = bf16(relu(states @ w_fc^T + b_fc)^2)
  gemm_h<1><<<dim3(4 * Ed / 128, BS / 128), 256, 0, stream>>>(
      statesh, wfc_h, b_fc, nullptr, hfh, BS, 4 * Ed, Hd, 4 * Ed, nullptr, nullptr, nullptr);
  // base_feat = hf @ w_hp^T + b_hp  (f32 + bf16 dual)
  gemm_h<2><<<dim3(Ed / 128, BS / 128), 256, 0, stream>>>(
      hfh, whp_h, b_hp, featb, feat_h, BS, Ed, 4 * Ed, Ed, nullptr, nullptr, nullptr);
  // base_logits = base_feat @ emb^T + out_bias  -> d_out
  gemm_h<0><<<dim3(Vd / 128, BS / 128), 256, 0, stream>>>(
      feat_h, embh, out_b, out, nullptr, BS, Vd, Ed, Vd, nullptr, nullptr, nullptr);
  // qkv = states @ [wq|wk|wv]^T + [bq|bk|bv]  (one N=1024 GEMM)
  gemm_h<0><<<dim3(1024 / 128, BS / 128), 256, 0, stream>>>(
      statesh, wqkv_h, bqkv, qkv, nullptr, BS, 1024, Hd, 1024, nullptr, nullptr, nullptr);
  // gate
  gate_kernel<<<BS / 4, 256, 0, stream>>>(statesh, wg, bg, gateb);
  // ctx = windowed attention; ffh = bf16(featb + gate*ms*ctx)
  attn_kernel<<<BS, 512, 0, stream>>>(qkv, featb, ffh, gateb, msc);
  // scatter: d_out[r, untied[c]] += fused_feat @ w_ph^T + (1+gate*ms)*b_ph
  gemm_h<3><<<dim3(Pd / 128, BS / 128), 256, 0, stream>>>(
      ffh, wph_h, b_ph, out, nullptr, BS, Pd, Ed, Vd, gateb, msc, untied);
}